// Round 12
// baseline (434.688 us; speedup 1.0000x reference)
//
#include <hip/hip_runtime.h>
#include <hip/hip_bf16.h>

#define NN 10000
#define EE 320000
#define ETOT (EE + NN)
#define CIN 256
#define HC 512
#define NHEAD 8
#define NEG 0.2f
#define NBKT 8
#define BKTW 1250  // NN / NBKT

#define SX (NN * CIN)
#define SATT (6 * 512)

using bf16x8 = __attribute__((ext_vector_type(8))) short;
using f32x4 = __attribute__((ext_vector_type(4))) float;
typedef unsigned short u16;
typedef unsigned int u32;

__device__ __forceinline__ u16 f2bf(float f) {
  __hip_bfloat16 b = __float2bfloat16(f);
  return *(u16*)&b;
}
__device__ __forceinline__ float bflo(u32 p) { return __uint_as_float(p << 16); }
__device__ __forceinline__ float bfhi(u32 p) { return __uint_as_float(p & 0xFFFF0000u); }

// ============ prep: detect + convert + bucketed degree-count + W transpose ==
#define PB_X ((SX + 255) / 256)
#define PB_ATT ((SATT + 255) / 256)
#define PB_CNT ((ETOT + 255) / 256)
#define PB_WT 96
#define PB_TOT (PB_X + PB_ATT + PB_CNT + PB_WT)

__global__ __launch_bounds__(256) void prep_k(
    const void* __restrict__ x, const void* __restrict__ w1,
    const void* __restrict__ w2,
    const void* a0, const void* a1, const void* a2,
    const void* a3, const void* a4, const void* a5,
    const int* __restrict__ ei,
    u16* __restrict__ xb, u16* __restrict__ w1t, u16* __restrict__ w2t,
    float* __restrict__ attf, int* __restrict__ counts, int* __restrict__ flag) {
  const int b = blockIdx.x, t = threadIdx.x;
  __shared__ int sbad;
  if (t == 0) sbad = 0;
  __syncthreads();
  {
    const u16* xu = (const u16*)x;
    unsigned e0 = (xu[2 * t] >> 7) & 0xFFu;
    unsigned e1 = (xu[2 * t + 1] >> 7) & 0xFFu;
    if (e0 >= 0xC8u || e1 >= 0xC8u) sbad = 1;
  }
  __syncthreads();
  const bool bf = (sbad == 0);
  if (b == 0 && t == 0) *flag = bf ? 1 : 0;

  if (b < PB_X) {
    if (!bf) {
      int i = b * 256 + t;
      if (i < SX) xb[i] = f2bf(((const float*)x)[i]);
    }
  } else if (b < PB_X + PB_ATT) {
    int j = (b - PB_X) * 256 + t;
    if (j < SATT) {
      const void* ps[6] = {a0, a1, a2, a3, a4, a5};
      const void* p = ps[j >> 9];
      int k = j & 511;
      attf[j] = bf ? __bfloat162float(((const __hip_bfloat16*)p)[k])
                   : ((const float*)p)[k];
    }
  } else if (b < PB_X + PB_ATT + PB_CNT) {
    int e = (b - PB_X - PB_ATT) * 256 + t;
    if (e < ETOT) {
      int d, s;
      if (e < EE) { s = ei[e]; d = ei[EE + e]; }
      else { s = d = e - EE; }
      int q = s / BKTW;
      atomicAdd(&counts[d * NBKT + q], 1);
    }
  } else {
    __shared__ u16 tile[64][72];
    int wb = b - (PB_X + PB_ATT + PB_CNT);
    const void* src;
    u16* dst;
    int K, tk, tn;
    if (wb < 32) { src = w1; dst = w1t; K = CIN; tk = (wb >> 3) * 64; tn = (wb & 7) * 64; }
    else { wb -= 32; src = w2; dst = w2t; K = HC; tk = (wb >> 3) * 64; tn = (wb & 7) * 64; }
    const int r = t >> 2, cb = (t & 3) * 16;
    if (bf) {
      const u16* s = (const u16*)src + (size_t)(tk + r) * HC + tn + cb;
      *(int4*)&tile[r][cb] = ((const int4*)s)[0];
      *(int4*)&tile[r][cb + 8] = ((const int4*)s)[1];
    } else {
      const float* s = (const float*)src + (size_t)(tk + r) * HC + tn + cb;
#pragma unroll
      for (int j = 0; j < 16; j++) tile[r][cb + j] = f2bf(s[j]);
    }
    __syncthreads();
    union { u16 o[16]; int4 v[2]; } u;
#pragma unroll
    for (int j = 0; j < 16; j++) u.o[j] = tile[cb + j][r];
    int4* dp = (int4*)(dst + (size_t)(tn + r) * K + tk + cb);
    dp[0] = u.v[0];
    dp[1] = u.v[1];
  }
}

// ============ scan over 8*NN bucket counts: rowptr4 + cursors ===============
// two-pass serial per thread (79 entries) + 1024-wide block scan.
#define SCNT (NBKT * NN)
#define SPER 79  // ceil(80000/1024)

__global__ __launch_bounds__(1024) void scan_k(const int* __restrict__ counts,
                                               int* __restrict__ rowptr4,
                                               int* __restrict__ wcur) {
  __shared__ int buf[1024];
  const int t = threadIdx.x;
  int s = 0;
  for (int j = 0; j < SPER; j++) {
    int i = t * SPER + j;
    if (i < SCNT) s += counts[i];
  }
  buf[t] = s;
  __syncthreads();
  for (int off = 1; off < 1024; off <<= 1) {
    int v = (t >= off) ? buf[t - off] : 0;
    __syncthreads();
    buf[t] += v;
    __syncthreads();
  }
  int run = (t > 0) ? buf[t - 1] : 0;
  for (int j = 0; j < SPER; j++) {
    int i = t * SPER + j;
    if (i < SCNT) {
      rowptr4[i] = run;
      wcur[i] = run;
      run += counts[i];
    }
  }
  if (t == 1023) rowptr4[SCNT] = buf[1023];
}

// ============ CSR fill (bucketed) ===========================================
__global__ void fill_k(const int* __restrict__ ei, const void* __restrict__ ew,
                       const int* __restrict__ flag, int* __restrict__ wcur,
                       int* __restrict__ esrc, float* __restrict__ elw) {
  int e = blockIdx.x * blockDim.x + threadIdx.x;
  if (e >= ETOT) return;
  int s, d;
  float lw;
  if (e < EE) {
    s = ei[e];
    d = ei[EE + e];
    float w = (*flag) ? __bfloat162float(((const __hip_bfloat16*)ew)[e])
                      : ((const float*)ew)[e];
    lw = log2f(w);
  } else {
    s = d = e - EE;
    lw = 0.f;
  }
  int q = s / BKTW;
  int pos = atomicAdd(&wcur[d * NBKT + q], 1);
  esrc[pos] = s;
  elw[pos] = lw;
}

// ============ MFMA GEMM + fused logits ======================================
#define BM 64
#define BN 128
#define BK 64
#define LSTR 72

__global__ __launch_bounds__(256) void gemm_mfma(const u16* __restrict__ A,
                                                 const void* __restrict__ Axalt,
                                                 const int* __restrict__ flagp,
                                                 const u16* __restrict__ Wt,
                                                 const float* __restrict__ as_w,
                                                 const float* __restrict__ ad_w,
                                                 u16* __restrict__ hb,
                                                 float* __restrict__ alsrc,
                                                 float* __restrict__ aldst,
                                                 int M, int K) {
  __shared__ u16 As[BM * LSTR];
  __shared__ u16 Bs[BN * LSTR];
  __shared__ float sps[2][2][BM], spd[2][2][BM];
  const u16* Asel = (flagp && *flagp) ? (const u16*)Axalt : A;
  const int bx = blockIdx.x;
  const int bm = blockIdx.y * BM, bn = bx * BN;
  const int t = threadIdx.x, wv = t >> 6, lane = t & 63;
  const int l15 = lane & 15, quad = lane >> 4;
  f32x4 acc[4][2] = {};
  for (int k0 = 0; k0 < K; k0 += BK) {
    {
      int row = t >> 2, kq = (t & 3) * 16;
      int gr = bm + row;
      int4 v0 = make_int4(0, 0, 0, 0), v1 = v0;
      if (gr < M) {
        const int4* gp = (const int4*)(Asel + (size_t)gr * K + k0 + kq);
        v0 = gp[0];
        v1 = gp[1];
      }
      int4* lp = (int4*)(As + row * LSTR + kq);
      lp[0] = v0;
      lp[1] = v1;
    }
    {
      int row = t >> 1, kq = (t & 1) * 32;
      const int4* gp = (const int4*)(Wt + (size_t)(bn + row) * K + k0 + kq);
      int4* lp = (int4*)(Bs + row * LSTR + kq);
      lp[0] = gp[0];
      lp[1] = gp[1];
      lp[2] = gp[2];
      lp[3] = gp[3];
    }
    __syncthreads();
#pragma unroll
    for (int kk = 0; kk < 2; kk++) {
      bf16x8 bfr[2];
#pragma unroll
      for (int ct = 0; ct < 2; ct++)
        bfr[ct] = *(const bf16x8*)(Bs + (wv * 32 + ct * 16 + l15) * LSTR + kk * 32 + quad * 8);
#pragma unroll
      for (int rt = 0; rt < 4; rt++) {
        bf16x8 af = *(const bf16x8*)(As + (rt * 16 + l15) * LSTR + kk * 32 + quad * 8);
#pragma unroll
        for (int ct = 0; ct < 2; ct++)
          acc[rt][ct] = __builtin_amdgcn_mfma_f32_16x16x32_bf16(af, bfr[ct],
                                                                acc[rt][ct], 0, 0, 0);
      }
    }
    __syncthreads();
  }
  const int head = bx * 2 + (wv >> 1);
  float asw[2], adw[2];
#pragma unroll
  for (int ct = 0; ct < 2; ct++) {
    int c = head * 64 + (wv & 1) * 32 + ct * 16 + l15;
    asw[ct] = as_w[c];
    adw[ct] = ad_w[c];
  }
#pragma unroll
  for (int rt = 0; rt < 4; rt++) {
#pragma unroll
    for (int r = 0; r < 4; r++) {
      int rib = rt * 16 + quad * 4 + r;
      int row = bm + rib;
      float ps = 0.f, pd = 0.f;
#pragma unroll
      for (int ct = 0; ct < 2; ct++) {
        float v = acc[rt][ct][r];
        ps += v * asw[ct];
        pd += v * adw[ct];
        if (row < M)
          hb[(size_t)row * HC + bn + wv * 32 + ct * 16 + l15] = f2bf(v);
      }
#pragma unroll
      for (int d = 1; d < 16; d <<= 1) {
        ps += __shfl_xor(ps, d);
        pd += __shfl_xor(pd, d);
      }
      if (l15 == 0) {
        sps[wv >> 1][wv & 1][rib] = ps;
        spd[wv >> 1][wv & 1][rib] = pd;
      }
    }
  }
  __syncthreads();
  if (t < 2 * BM) {
    int rib = t & 63, hs = t >> 6;
    int row = bm + rib;
    if (row < M) {
      alsrc[row * NHEAD + bx * 2 + hs] = sps[hs][0][rib] + sps[hs][1][rib];
      aldst[row * NHEAD + bx * 2 + hs] = spd[hs][0][rib] + spd[hs][1][rib];
    }
  }
}

// ============ barrier-free per-wave softmax + src-ordered aggregation =======
// One WAVE per dst node; edges pre-sorted into 8 src-range buckets (1.25 MB of
// hb each) by the CSR build. Pass B = round-10 whole-row int4 x4-unrolled
// gather; sequential iteration visits low-src buckets first, so the resident
// wave cohort's reads stay inside a ~1.25-3 MB window < 4 MiB per-XCD L2.
#define ACC8(P, W)                                                             \
  {                                                                            \
    const u32 q0 = (u32)(P).x, q1 = (u32)(P).y, q2 = (u32)(P).z, q3 = (u32)(P).w; \
    acc[0] += (W)*bflo(q0);                                                    \
    acc[1] += (W)*bfhi(q0);                                                    \
    acc[2] += (W)*bflo(q1);                                                    \
    acc[3] += (W)*bfhi(q1);                                                    \
    acc[4] += (W)*bflo(q2);                                                    \
    acc[5] += (W)*bfhi(q2);                                                    \
    acc[6] += (W)*bflo(q3);                                                    \
    acc[7] += (W)*bfhi(q3);                                                    \
  }

template <bool RELU, bool FINAL>
__global__ __launch_bounds__(256) void agg_k(const u16* __restrict__ hb,
                                             const float* __restrict__ alsrc,
                                             const float* __restrict__ aldst,
                                             const int* __restrict__ rowptr4,
                                             const int* __restrict__ esrc,
                                             const float* __restrict__ elw,
                                             const float* __restrict__ bias,
                                             u32* __restrict__ outB,
                                             float* __restrict__ outF,
                                             const int* __restrict__ flag) {
  const int t = threadIdx.x;
  const int wv = t >> 6, lane = t & 63;
  const int n = blockIdx.x * 4 + wv;
  const int h = lane & 7, eo = lane >> 3;
  const int hh = lane >> 3;
  const int chbase = lane * 8;
  __shared__ float swA[4][NHEAD][132];
  __shared__ int ssA[4][128];
  float (*const swv)[132] = swA[wv];
  int* const ssv = ssA[wv];
  const int beg = rowptr4[n * NBKT];
  const int deg = rowptr4[n * NBKT + NBKT] - beg;
  const float aln = aldst[(size_t)n * NHEAD + h];
  float acc[8] = {};
  float inv;

  if (deg <= 128) {
    // ---- A1: alpha -> LDS, per-head max (shfl-only) ----
    float m = -1e30f;
    for (int j = eo; j < deg; j += 8) {
      int e = beg + j;
      int s = esrc[e];
      float a = alsrc[(size_t)s * NHEAD + h] + aln;
      a = (a > 0.f) ? a : NEG * a;
      a += elw[e];
      swv[h][j] = a;
      m = fmaxf(m, a);
      if (h == 0) ssv[j] = s;
    }
    m = fmaxf(m, __shfl_xor(m, 8));
    m = fmaxf(m, __shfl_xor(m, 16));
    m = fmaxf(m, __shfl_xor(m, 32));
    // ---- A2: exp in place + denom ----
    float sum = 0.f;
    for (int j = eo; j < deg; j += 8) {
      float w = expf(swv[h][j] - m);
      swv[h][j] = w;
      sum += w;
    }
    sum += __shfl_xor(sum, 8);
    sum += __shfl_xor(sum, 16);
    sum += __shfl_xor(sum, 32);
    inv = 1.f / __shfl(sum, hh);
    // ---- B: sequential (src-bucket-ordered) edges, x4 unrolled ----
    int i = 0;
    for (; i + 3 < deg; i += 4) {
      const int s0 = ssv[i], s1 = ssv[i + 1], s2 = ssv[i + 2], s3 = ssv[i + 3];
      const float w0 = swv[hh][i], w1 = swv[hh][i + 1];
      const float w2 = swv[hh][i + 2], w3 = swv[hh][i + 3];
      const int4 p0 = *(const int4*)(hb + (size_t)s0 * HC + chbase);
      const int4 p1 = *(const int4*)(hb + (size_t)s1 * HC + chbase);
      const int4 p2 = *(const int4*)(hb + (size_t)s2 * HC + chbase);
      const int4 p3 = *(const int4*)(hb + (size_t)s3 * HC + chbase);
      ACC8(p0, w0)
      ACC8(p1, w1)
      ACC8(p2, w2)
      ACC8(p3, w3)
    }
    for (; i < deg; i++) {
      const int s = ssv[i];
      const float w = swv[hh][i];
      const int4 p = *(const int4*)(hb + (size_t)s * HC + chbase);
      ACC8(p, w)
    }
  } else {
    // ---- slow path (deg > 128): streaming recompute, barrier-free ----
    float m = -1e30f;
    for (int j = eo; j < deg; j += 8) {
      int e = beg + j;
      float a = alsrc[(size_t)esrc[e] * NHEAD + h] + aln;
      a = (a > 0.f) ? a : NEG * a;
      m = fmaxf(m, a + elw[e]);
    }
    m = fmaxf(m, __shfl_xor(m, 8));
    m = fmaxf(m, __shfl_xor(m, 16));
    m = fmaxf(m, __shfl_xor(m, 32));
    float sum = 0.f;
    for (int j = eo; j < deg; j += 8) {
      int e = beg + j;
      float a = alsrc[(size_t)esrc[e] * NHEAD + h] + aln;
      a = (a > 0.f) ? a : NEG * a;
      sum += expf(a + elw[e] - m);
    }
    sum += __shfl_xor(sum, 8);
    sum += __shfl_xor(sum, 16);
    sum += __shfl_xor(sum, 32);
    inv = 1.f / __shfl(sum, hh);
    const float mh = __shfl(m, hh);
    const float alnh = __shfl(aln, hh);
    for (int i = 0; i < deg; i++) {
      int e = beg + i;
      int s = esrc[e];
      float a = alsrc[(size_t)s * NHEAD + hh] + alnh;
      a = (a > 0.f) ? a : NEG * a;
      float w = expf(a + elw[e] - mh);
      const int4 p = *(const int4*)(hb + (size_t)s * HC + chbase);
      ACC8(p, w)
    }
  }
  // ---- epilogue ----
  const float4 b0 = *(const float4*)(bias + chbase);
  const float4 b1 = *(const float4*)(bias + chbase + 4);
  float v[8];
  v[0] = acc[0] * inv + b0.x; v[1] = acc[1] * inv + b0.y;
  v[2] = acc[2] * inv + b0.z; v[3] = acc[3] * inv + b0.w;
  v[4] = acc[4] * inv + b1.x; v[5] = acc[5] * inv + b1.y;
  v[6] = acc[6] * inv + b1.z; v[7] = acc[7] * inv + b1.w;
  if (RELU) {
#pragma unroll
    for (int k = 0; k < 8; k++) v[k] = fmaxf(v[k], 0.f);
  }
  if (FINAL && !(*flag)) {
    float4* op = (float4*)(outF + (size_t)n * HC + chbase);
    op[0] = make_float4(v[0], v[1], v[2], v[3]);
    op[1] = make_float4(v[4], v[5], v[6], v[7]);
  } else {
    int4 pk;
    pk.x = (int)((u32)f2bf(v[0]) | ((u32)f2bf(v[1]) << 16));
    pk.y = (int)((u32)f2bf(v[2]) | ((u32)f2bf(v[3]) << 16));
    pk.z = (int)((u32)f2bf(v[4]) | ((u32)f2bf(v[5]) << 16));
    pk.w = (int)((u32)f2bf(v[6]) | ((u32)f2bf(v[7]) << 16));
    *(int4*)(outB + (size_t)n * (HC / 2) + lane * 4) = pk;
  }
}

// ---------------- workspace layout -----------------------------------------
static constexpr size_t algn(size_t x) { return (x + 255) & ~(size_t)255; }
static constexpr size_t oFlag = 0;
static constexpr size_t oXB = algn(oFlag + 256);
static constexpr size_t oW1T = algn(oXB + (size_t)SX * 2);
static constexpr size_t oW2T = algn(oW1T + (size_t)CIN * HC * 2);
static constexpr size_t oAtt = algn(oW2T + (size_t)HC * HC * 2);
static constexpr size_t oHB = algn(oAtt + (size_t)SATT * 4);
static constexpr size_t oO1B = algn(oHB + (size_t)NN * HC * 2);
static constexpr size_t oAS = algn(oO1B + (size_t)NN * HC * 2);
static constexpr size_t oAD = algn(oAS + (size_t)NN * NHEAD * 4);
static constexpr size_t oCnt = algn(oAD + (size_t)NN * NHEAD * 4);
static constexpr size_t oRP4 = algn(oCnt + (size_t)SCNT * 4);
static constexpr size_t oWcur = algn(oRP4 + (size_t)(SCNT + 1) * 4);
static constexpr size_t oESrc = algn(oWcur + (size_t)SCNT * 4);
static constexpr size_t oELW = algn(oESrc + (size_t)ETOT * 4);

extern "C" void kernel_launch(void* const* d_in, const int* in_sizes, int n_in,
                              void* d_out, int out_size, void* d_ws, size_t ws_size,
                              hipStream_t stream) {
  (void)in_sizes; (void)n_in; (void)out_size; (void)ws_size;
  const int* ei = (const int*)d_in[1];

  char* ws = (char*)d_ws;
  int* flag = (int*)(ws + oFlag);
  u16* xb = (u16*)(ws + oXB);
  u16* w1t = (u16*)(ws + oW1T);
  u16* w2t = (u16*)(ws + oW2T);
  float* attf = (float*)(ws + oAtt);
  float* as1f = attf, *ad1f = attf + 512, *b1f = attf + 1024;
  float* as2f = attf + 1536, *ad2f = attf + 2048, *b2f = attf + 2560;
  u16* hb = (u16*)(ws + oHB);
  u16* o1b = (u16*)(ws + oO1B);
  float* alsrc = (float*)(ws + oAS);
  float* aldst = (float*)(ws + oAD);
  int* counts = (int*)(ws + oCnt);
  int* rowptr4 = (int*)(ws + oRP4);
  int* wcur = (int*)(ws + oWcur);
  int* esrc = (int*)(ws + oESrc);
  float* elw = (float*)(ws + oELW);

  hipMemsetAsync(counts, 0, (size_t)SCNT * 4, stream);
  prep_k<<<PB_TOT, 256, 0, stream>>>(d_in[0], d_in[3], d_in[7],
                                     d_in[4], d_in[5], d_in[6],
                                     d_in[8], d_in[9], d_in[10], ei,
                                     xb, w1t, w2t, attf, counts, flag);
  scan_k<<<1, 1024, 0, stream>>>(counts, rowptr4, wcur);
  fill_k<<<(ETOT + 255) / 256, 256, 0, stream>>>(ei, d_in[2], flag, wcur, esrc, elw);

  // ---- layer 1 ----
  gemm_mfma<<<dim3(HC / BN, (NN + BM - 1) / BM), 256, 0, stream>>>(
      xb, d_in[0], flag, w1t, as1f, ad1f, hb, alsrc, aldst, NN, CIN);
  agg_k<true, false><<<NN / 4, 256, 0, stream>>>(hb, alsrc, aldst, rowptr4, esrc, elw,
                                                 b1f, (u32*)o1b, nullptr, flag);

  // ---- layer 2 ----
  gemm_mfma<<<dim3(HC / BN, (NN + BM - 1) / BM), 256, 0, stream>>>(
      o1b, nullptr, nullptr, w2t, as2f, ad2f, hb, alsrc, aldst, NN, HC);
  agg_k<false, true><<<NN / 4, 256, 0, stream>>>(hb, alsrc, aldst, rowptr4, esrc, elw,
                                                 b2f, (u32*)d_out, (float*)d_out, flag);
}

// Round 13
// 258.183 us; speedup vs baseline: 1.6836x; 1.6836x over previous
//
#include <hip/hip_runtime.h>
#include <hip/hip_bf16.h>

#define NN 10000
#define EE 320000
#define ETOT (EE + NN)
#define CIN 256
#define HC 512
#define NHEAD 8
#define NEG 0.2f
#define NBKT 8
#define BKTW 1250

#define SX (NN * CIN)
#define SATT (6 * 512)

using bf16x8 = __attribute__((ext_vector_type(8))) short;
using f32x4 = __attribute__((ext_vector_type(4))) float;
typedef unsigned short u16;
typedef unsigned int u32;
typedef unsigned long long u64;

__device__ __forceinline__ u16 f2bf(float f) {
  __hip_bfloat16 b = __float2bfloat16(f);
  return *(u16*)&b;
}
__device__ __forceinline__ float bflo(u32 p) { return __uint_as_float(p << 16); }
__device__ __forceinline__ float bfhi(u32 p) { return __uint_as_float(p & 0xFFFF0000u); }

// ============ prep: detect + convert + degree-count + W transpose ==========
#define PB_X ((SX + 255) / 256)
#define PB_ATT ((SATT + 255) / 256)
#define PB_CNT ((ETOT + 255) / 256)
#define PB_WT 96
#define PB_TOT (PB_X + PB_ATT + PB_CNT + PB_WT)

__global__ __launch_bounds__(256) void prep_k(
    const void* __restrict__ x, const void* __restrict__ w1,
    const void* __restrict__ w2,
    const void* a0, const void* a1, const void* a2,
    const void* a3, const void* a4, const void* a5,
    const int* __restrict__ ei,
    u16* __restrict__ xb, u16* __restrict__ w1t, u16* __restrict__ w2t,
    float* __restrict__ attf, int* __restrict__ counts, int* __restrict__ flag) {
  const int b = blockIdx.x, t = threadIdx.x;
  __shared__ int sbad;
  if (t == 0) sbad = 0;
  __syncthreads();
  {
    const u16* xu = (const u16*)x;
    unsigned e0 = (xu[2 * t] >> 7) & 0xFFu;
    unsigned e1 = (xu[2 * t + 1] >> 7) & 0xFFu;
    if (e0 >= 0xC8u || e1 >= 0xC8u) sbad = 1;
  }
  __syncthreads();
  const bool bf = (sbad == 0);
  if (b == 0 && t == 0) *flag = bf ? 1 : 0;

  if (b < PB_X) {
    if (!bf) {
      int i = b * 256 + t;
      if (i < SX) xb[i] = f2bf(((const float*)x)[i]);
    }
  } else if (b < PB_X + PB_ATT) {
    int j = (b - PB_X) * 256 + t;
    if (j < SATT) {
      const void* ps[6] = {a0, a1, a2, a3, a4, a5};
      const void* p = ps[j >> 9];
      int k = j & 511;
      attf[j] = bf ? __bfloat162float(((const __hip_bfloat16*)p)[k])
                   : ((const float*)p)[k];
    }
  } else if (b < PB_X + PB_ATT + PB_CNT) {
    int e = (b - PB_X - PB_ATT) * 256 + t;
    if (e < ETOT) {
      int d = (e < EE) ? ei[EE + e] : (e - EE);
      atomicAdd(&counts[d], 1);
    }
  } else {
    __shared__ u16 tile[64][72];
    int wb = b - (PB_X + PB_ATT + PB_CNT);
    const void* src;
    u16* dst;
    int K, tk, tn;
    if (wb < 32) { src = w1; dst = w1t; K = CIN; tk = (wb >> 3) * 64; tn = (wb & 7) * 64; }
    else { wb -= 32; src = w2; dst = w2t; K = HC; tk = (wb >> 3) * 64; tn = (wb & 7) * 64; }
    const int r = t >> 2, cb = (t & 3) * 16;
    if (bf) {
      const u16* s = (const u16*)src + (size_t)(tk + r) * HC + tn + cb;
      *(int4*)&tile[r][cb] = ((const int4*)s)[0];
      *(int4*)&tile[r][cb + 8] = ((const int4*)s)[1];
    } else {
      const float* s = (const float*)src + (size_t)(tk + r) * HC + tn + cb;
#pragma unroll
      for (int j = 0; j < 16; j++) tile[r][cb + j] = f2bf(s[j]);
    }
    __syncthreads();
    union { u16 o[16]; int4 v[2]; } u;
#pragma unroll
    for (int j = 0; j < 16; j++) u.o[j] = tile[cb + j][r];
    int4* dp = (int4*)(dst + (size_t)(tn + r) * K + tk + cb);
    dp[0] = u.v[0];
    dp[1] = u.v[1];
  }
}

// ============ exclusive scan over NN: rowptr + working cursors ==============
__global__ __launch_bounds__(1024) void scan_k(const int* __restrict__ counts,
                                               int* __restrict__ rowptr,
                                               int* __restrict__ wcur) {
  __shared__ int buf[1024];
  const int t = threadIdx.x;
  int loc[10];
  int s = 0;
#pragma unroll
  for (int j = 0; j < 10; j++) {
    int i = t * 10 + j;
    s += (i < NN) ? counts[i] : 0;
    loc[j] = s;
  }
  buf[t] = s;
  __syncthreads();
  for (int off = 1; off < 1024; off <<= 1) {
    int v = (t >= off) ? buf[t - off] : 0;
    __syncthreads();
    buf[t] += v;
    __syncthreads();
  }
  int base = (t > 0) ? buf[t - 1] : 0;
  int prev = 0;
#pragma unroll
  for (int j = 0; j < 10; j++) {
    int i = t * 10 + j;
    if (i < NN) {
      rowptr[i + 1] = base + loc[j];
      wcur[i] = base + prev;
    }
    prev = loc[j];
  }
  if (t == 0) rowptr[0] = 0;
}

// ============ CSR fill ======================================================
__global__ void fill_k(const int* __restrict__ ei, const void* __restrict__ ew,
                       const int* __restrict__ flag, int* __restrict__ wcur,
                       int* __restrict__ esrc, float* __restrict__ elw) {
  int e = blockIdx.x * blockDim.x + threadIdx.x;
  if (e >= ETOT) return;
  int s, d;
  float lw;
  if (e < EE) {
    s = ei[e];
    d = ei[EE + e];
    float w = (*flag) ? __bfloat162float(((const __hip_bfloat16*)ew)[e])
                      : ((const float*)ew)[e];
    lw = log2f(w);
  } else {
    s = d = e - EE;
    lw = 0.f;
  }
  int pos = atomicAdd(&wcur[d], 1);
  esrc[pos] = s;
  elw[pos] = lw;
}

// ============ wave-local src-bucket reorder (no global scan) ================
// One wave per node: permute its <=128 edges into ascending src-bucket order
// via ballot/popcount ranking in registers. Cohort of concurrent agg waves
// then sweeps hb low->high together -> working window fits 4 MiB per-XCD L2.
__global__ __launch_bounds__(256) void reorder_k(const int* __restrict__ rowptr,
                                                 const int* __restrict__ esrc,
                                                 const float* __restrict__ elw,
                                                 int* __restrict__ esrc2,
                                                 float* __restrict__ elw2) {
  const int t = threadIdx.x;
  const int wv = t >> 6, lane = t & 63;
  const int n = blockIdx.x * 4 + wv;
  const int beg = rowptr[n];
  const int deg = rowptr[n + 1] - beg;
  if (deg <= 128) {
    int src[2];
    float lw[2];
    int bkt[2] = {-1, -1};
#pragma unroll
    for (int c = 0; c < 2; c++) {
      int j = c * 64 + lane;
      if (j < deg) {
        src[c] = esrc[beg + j];
        lw[c] = elw[beg + j];
        bkt[c] = src[c] / BKTW;
      }
    }
    u64 B[2][NBKT];
#pragma unroll
    for (int c = 0; c < 2; c++)
#pragma unroll
      for (int q = 0; q < NBKT; q++) B[c][q] = __ballot(bkt[c] == q);
    int start[NBKT];
    int run = 0;
#pragma unroll
    for (int q = 0; q < NBKT; q++) {
      start[q] = run;
      run += __popcll(B[0][q]) + __popcll(B[1][q]);
    }
    const u64 ltmask = (lane == 63) ? 0x7FFFFFFFFFFFFFFFull : ((1ull << lane) - 1);
#pragma unroll
    for (int c = 0; c < 2; c++) {
      int j = c * 64 + lane;
      if (j < deg) {
        int q = bkt[c];
        int rank = __popcll(B[c][q] & ltmask) + (c == 1 ? __popcll(B[0][q]) : 0);
        int pos = beg + start[q] + rank;
        esrc2[pos] = src[c];
        elw2[pos] = lw[c];
      }
    }
  } else {
    for (int j = lane; j < deg; j += 64) {
      esrc2[beg + j] = esrc[beg + j];
      elw2[beg + j] = elw[beg + j];
    }
  }
}

// ============ MFMA GEMM + fused logits ======================================
#define BM 64
#define BN 128
#define BK 64
#define LSTR 72

__global__ __launch_bounds__(256) void gemm_mfma(const u16* __restrict__ A,
                                                 const void* __restrict__ Axalt,
                                                 const int* __restrict__ flagp,
                                                 const u16* __restrict__ Wt,
                                                 const float* __restrict__ as_w,
                                                 const float* __restrict__ ad_w,
                                                 u16* __restrict__ hb,
                                                 float* __restrict__ alsrc,
                                                 float* __restrict__ aldst,
                                                 int M, int K) {
  __shared__ u16 As[BM * LSTR];
  __shared__ u16 Bs[BN * LSTR];
  __shared__ float sps[2][2][BM], spd[2][2][BM];
  const u16* Asel = (flagp && *flagp) ? (const u16*)Axalt : A;
  const int bx = blockIdx.x;
  const int bm = blockIdx.y * BM, bn = bx * BN;
  const int t = threadIdx.x, wv = t >> 6, lane = t & 63;
  const int l15 = lane & 15, quad = lane >> 4;
  f32x4 acc[4][2] = {};
  for (int k0 = 0; k0 < K; k0 += BK) {
    {
      int row = t >> 2, kq = (t & 3) * 16;
      int gr = bm + row;
      int4 v0 = make_int4(0, 0, 0, 0), v1 = v0;
      if (gr < M) {
        const int4* gp = (const int4*)(Asel + (size_t)gr * K + k0 + kq);
        v0 = gp[0];
        v1 = gp[1];
      }
      int4* lp = (int4*)(As + row * LSTR + kq);
      lp[0] = v0;
      lp[1] = v1;
    }
    {
      int row = t >> 1, kq = (t & 1) * 32;
      const int4* gp = (const int4*)(Wt + (size_t)(bn + row) * K + k0 + kq);
      int4* lp = (int4*)(Bs + row * LSTR + kq);
      lp[0] = gp[0];
      lp[1] = gp[1];
      lp[2] = gp[2];
      lp[3] = gp[3];
    }
    __syncthreads();
#pragma unroll
    for (int kk = 0; kk < 2; kk++) {
      bf16x8 bfr[2];
#pragma unroll
      for (int ct = 0; ct < 2; ct++)
        bfr[ct] = *(const bf16x8*)(Bs + (wv * 32 + ct * 16 + l15) * LSTR + kk * 32 + quad * 8);
#pragma unroll
      for (int rt = 0; rt < 4; rt++) {
        bf16x8 af = *(const bf16x8*)(As + (rt * 16 + l15) * LSTR + kk * 32 + quad * 8);
#pragma unroll
        for (int ct = 0; ct < 2; ct++)
          acc[rt][ct] = __builtin_amdgcn_mfma_f32_16x16x32_bf16(af, bfr[ct],
                                                                acc[rt][ct], 0, 0, 0);
      }
    }
    __syncthreads();
  }
  const int head = bx * 2 + (wv >> 1);
  float asw[2], adw[2];
#pragma unroll
  for (int ct = 0; ct < 2; ct++) {
    int c = head * 64 + (wv & 1) * 32 + ct * 16 + l15;
    asw[ct] = as_w[c];
    adw[ct] = ad_w[c];
  }
#pragma unroll
  for (int rt = 0; rt < 4; rt++) {
#pragma unroll
    for (int r = 0; r < 4; r++) {
      int rib = rt * 16 + quad * 4 + r;
      int row = bm + rib;
      float ps = 0.f, pd = 0.f;
#pragma unroll
      for (int ct = 0; ct < 2; ct++) {
        float v = acc[rt][ct][r];
        ps += v * asw[ct];
        pd += v * adw[ct];
        if (row < M)
          hb[(size_t)row * HC + bn + wv * 32 + ct * 16 + l15] = f2bf(v);
      }
#pragma unroll
      for (int d = 1; d < 16; d <<= 1) {
        ps += __shfl_xor(ps, d);
        pd += __shfl_xor(pd, d);
      }
      if (l15 == 0) {
        sps[wv >> 1][wv & 1][rib] = ps;
        spd[wv >> 1][wv & 1][rib] = pd;
      }
    }
  }
  __syncthreads();
  if (t < 2 * BM) {
    int rib = t & 63, hs = t >> 6;
    int row = bm + rib;
    if (row < M) {
      alsrc[row * NHEAD + bx * 2 + hs] = sps[hs][0][rib] + sps[hs][1][rib];
      aldst[row * NHEAD + bx * 2 + hs] = spd[hs][0][rib] + spd[hs][1][rib];
    }
  }
}

// ============ barrier-free per-wave softmax + src-ordered aggregation =======
#define ACC8(P, W)                                                             \
  {                                                                            \
    const u32 q0 = (u32)(P).x, q1 = (u32)(P).y, q2 = (u32)(P).z, q3 = (u32)(P).w; \
    acc[0] += (W)*bflo(q0);                                                    \
    acc[1] += (W)*bfhi(q0);                                                    \
    acc[2] += (W)*bflo(q1);                                                    \
    acc[3] += (W)*bfhi(q1);                                                    \
    acc[4] += (W)*bflo(q2);                                                    \
    acc[5] += (W)*bfhi(q2);                                                    \
    acc[6] += (W)*bflo(q3);                                                    \
    acc[7] += (W)*bfhi(q3);                                                    \
  }

template <bool RELU, bool FINAL>
__global__ __launch_bounds__(256) void agg_k(const u16* __restrict__ hb,
                                             const float* __restrict__ alsrc,
                                             const float* __restrict__ aldst,
                                             const int* __restrict__ rowptr,
                                             const int* __restrict__ esrc,
                                             const float* __restrict__ elw,
                                             const float* __restrict__ bias,
                                             u32* __restrict__ outB,
                                             float* __restrict__ outF,
                                             const int* __restrict__ flag) {
  const int t = threadIdx.x;
  const int wv = t >> 6, lane = t & 63;
  const int n = blockIdx.x * 4 + wv;
  const int h = lane & 7, eo = lane >> 3;
  const int hh = lane >> 3;
  const int chbase = lane * 8;
  __shared__ float swA[4][NHEAD][132];
  __shared__ int ssA[4][128];
  float (*const swv)[132] = swA[wv];
  int* const ssv = ssA[wv];
  const int beg = rowptr[n];
  const int deg = rowptr[n + 1] - beg;
  const float aln = aldst[(size_t)n * NHEAD + h];
  float acc[8] = {};
  float inv;

  if (deg <= 128) {
    float m = -1e30f;
    for (int j = eo; j < deg; j += 8) {
      int e = beg + j;
      int s = esrc[e];
      float a = alsrc[(size_t)s * NHEAD + h] + aln;
      a = (a > 0.f) ? a : NEG * a;
      a += elw[e];
      swv[h][j] = a;
      m = fmaxf(m, a);
      if (h == 0) ssv[j] = s;
    }
    m = fmaxf(m, __shfl_xor(m, 8));
    m = fmaxf(m, __shfl_xor(m, 16));
    m = fmaxf(m, __shfl_xor(m, 32));
    float sum = 0.f;
    for (int j = eo; j < deg; j += 8) {
      float w = expf(swv[h][j] - m);
      swv[h][j] = w;
      sum += w;
    }
    sum += __shfl_xor(sum, 8);
    sum += __shfl_xor(sum, 16);
    sum += __shfl_xor(sum, 32);
    inv = 1.f / __shfl(sum, hh);
    int i = 0;
    for (; i + 3 < deg; i += 4) {
      const int s0 = ssv[i], s1 = ssv[i + 1], s2 = ssv[i + 2], s3 = ssv[i + 3];
      const float w0 = swv[hh][i], w1 = swv[hh][i + 1];
      const float w2 = swv[hh][i + 2], w3 = swv[hh][i + 3];
      const int4 p0 = *(const int4*)(hb + (size_t)s0 * HC + chbase);
      const int4 p1 = *(const int4*)(hb + (size_t)s1 * HC + chbase);
      const int4 p2 = *(const int4*)(hb + (size_t)s2 * HC + chbase);
      const int4 p3 = *(const int4*)(hb + (size_t)s3 * HC + chbase);
      ACC8(p0, w0)
      ACC8(p1, w1)
      ACC8(p2, w2)
      ACC8(p3, w3)
    }
    for (; i < deg; i++) {
      const int s = ssv[i];
      const float w = swv[hh][i];
      const int4 p = *(const int4*)(hb + (size_t)s * HC + chbase);
      ACC8(p, w)
    }
  } else {
    float m = -1e30f;
    for (int j = eo; j < deg; j += 8) {
      int e = beg + j;
      float a = alsrc[(size_t)esrc[e] * NHEAD + h] + aln;
      a = (a > 0.f) ? a : NEG * a;
      m = fmaxf(m, a + elw[e]);
    }
    m = fmaxf(m, __shfl_xor(m, 8));
    m = fmaxf(m, __shfl_xor(m, 16));
    m = fmaxf(m, __shfl_xor(m, 32));
    float sum = 0.f;
    for (int j = eo; j < deg; j += 8) {
      int e = beg + j;
      float a = alsrc[(size_t)esrc[e] * NHEAD + h] + aln;
      a = (a > 0.f) ? a : NEG * a;
      sum += expf(a + elw[e] - m);
    }
    sum += __shfl_xor(sum, 8);
    sum += __shfl_xor(sum, 16);
    sum += __shfl_xor(sum, 32);
    inv = 1.f / __shfl(sum, hh);
    const float mh = __shfl(m, hh);
    const float alnh = __shfl(aln, hh);
    for (int i = 0; i < deg; i++) {
      int e = beg + i;
      int s = esrc[e];
      float a = alsrc[(size_t)s * NHEAD + hh] + alnh;
      a = (a > 0.f) ? a : NEG * a;
      float w = expf(a + elw[e] - mh);
      const int4 p = *(const int4*)(hb + (size_t)s * HC + chbase);
      ACC8(p, w)
    }
  }
  const float4 b0 = *(const float4*)(bias + chbase);
  const float4 b1 = *(const float4*)(bias + chbase + 4);
  float v[8];
  v[0] = acc[0] * inv + b0.x; v[1] = acc[1] * inv + b0.y;
  v[2] = acc[2] * inv + b0.z; v[3] = acc[3] * inv + b0.w;
  v[4] = acc[4] * inv + b1.x; v[5] = acc[5] * inv + b1.y;
  v[6] = acc[6] * inv + b1.z; v[7] = acc[7] * inv + b1.w;
  if (RELU) {
#pragma unroll
    for (int k = 0; k < 8; k++) v[k] = fmaxf(v[k], 0.f);
  }
  if (FINAL && !(*flag)) {
    float4* op = (float4*)(outF + (size_t)n * HC + chbase);
    op[0] = make_float4(v[0], v[1], v[2], v[3]);
    op[1] = make_float4(v[4], v[5], v[6], v[7]);
  } else {
    int4 pk;
    pk.x = (int)((u32)f2bf(v[0]) | ((u32)f2bf(v[1]) << 16));
    pk.y = (int)((u32)f2bf(v[2]) | ((u32)f2bf(v[3]) << 16));
    pk.z = (int)((u32)f2bf(v[4]) | ((u32)f2bf(v[5]) << 16));
    pk.w = (int)((u32)f2bf(v[6]) | ((u32)f2bf(v[7]) << 16));
    *(int4*)(outB + (size_t)n * (HC / 2) + lane * 4) = pk;
  }
}

// ---------------- workspace layout -----------------------------------------
static constexpr size_t algn(size_t x) { return (x + 255) & ~(size_t)255; }
static constexpr size_t oFlag = 0;
static constexpr size_t oXB = algn(oFlag + 256);
static constexpr size_t oW1T = algn(oXB + (size_t)SX * 2);
static constexpr size_t oW2T = algn(oW1T + (size_t)CIN * HC * 2);
static constexpr size_t oAtt = algn(oW2T + (size_t)HC * HC * 2);
static constexpr size_t oHB = algn(oAtt + (size_t)SATT * 4);
static constexpr size_t oO1B = algn(oHB + (size_t)NN * HC * 2);
static constexpr size_t oAS = algn(oO1B + (size_t)NN * HC * 2);
static constexpr size_t oAD = algn(oAS + (size_t)NN * NHEAD * 4);
static constexpr size_t oRP = algn(oAD + (size_t)NN * NHEAD * 4);
static constexpr size_t oCnt = algn(oRP + (size_t)(NN + 1) * 4);
static constexpr size_t oWcur = algn(oCnt + (size_t)NN * 4);
static constexpr size_t oESrc = algn(oWcur + (size_t)NN * 4);
static constexpr size_t oELW = algn(oESrc + (size_t)ETOT * 4);
static constexpr size_t oESrc2 = algn(oELW + (size_t)ETOT * 4);
static constexpr size_t oELW2 = algn(oESrc2 + (size_t)ETOT * 4);

extern "C" void kernel_launch(void* const* d_in, const int* in_sizes, int n_in,
                              void* d_out, int out_size, void* d_ws, size_t ws_size,
                              hipStream_t stream) {
  (void)in_sizes; (void)n_in; (void)out_size; (void)ws_size;
  const int* ei = (const int*)d_in[1];

  char* ws = (char*)d_ws;
  int* flag = (int*)(ws + oFlag);
  u16* xb = (u16*)(ws + oXB);
  u16* w1t = (u16*)(ws + oW1T);
  u16* w2t = (u16*)(ws + oW2T);
  float* attf = (float*)(ws + oAtt);
  float* as1f = attf, *ad1f = attf + 512, *b1f = attf + 1024;
  float* as2f = attf + 1536, *ad2f = attf + 2048, *b2f = attf + 2560;
  u16* hb = (u16*)(ws + oHB);
  u16* o1b = (u16*)(ws + oO1B);
  float* alsrc = (float*)(ws + oAS);
  float* aldst = (float*)(ws + oAD);
  int* rowptr = (int*)(ws + oRP);
  int* counts = (int*)(ws + oCnt);
  int* wcur = (int*)(ws + oWcur);
  int* esrc = (int*)(ws + oESrc);
  float* elw = (float*)(ws + oELW);
  int* esrc2 = (int*)(ws + oESrc2);
  float* elw2 = (float*)(ws + oELW2);

  hipMemsetAsync(counts, 0, (size_t)NN * 4, stream);
  prep_k<<<PB_TOT, 256, 0, stream>>>(d_in[0], d_in[3], d_in[7],
                                     d_in[4], d_in[5], d_in[6],
                                     d_in[8], d_in[9], d_in[10], ei,
                                     xb, w1t, w2t, attf, counts, flag);
  scan_k<<<1, 1024, 0, stream>>>(counts, rowptr, wcur);
  fill_k<<<(ETOT + 255) / 256, 256, 0, stream>>>(ei, d_in[2], flag, wcur, esrc, elw);
  reorder_k<<<NN / 4, 256, 0, stream>>>(rowptr, esrc, elw, esrc2, elw2);

  // ---- layer 1 ----
  gemm_mfma<<<dim3(HC / BN, (NN + BM - 1) / BM), 256, 0, stream>>>(
      xb, d_in[0], flag, w1t, as1f, ad1f, hb, alsrc, aldst, NN, CIN);
  agg_k<true, false><<<NN / 4, 256, 0, stream>>>(hb, alsrc, aldst, rowptr, esrc2, elw2,
                                                 b1f, (u32*)o1b, nullptr, flag);

  // ---- layer 2 ----
  gemm_mfma<<<dim3(HC / BN, (NN + BM - 1) / BM), 256, 0, stream>>>(
      o1b, nullptr, nullptr, w2t, as2f, ad2f, hb, alsrc, aldst, NN, HC);
  agg_k<false, true><<<NN / 4, 256, 0, stream>>>(hb, alsrc, aldst, rowptr, esrc2, elw2,
                                                 b2f, (u32*)d_out, (float*)d_out, flag);
}